// Round 8
// baseline (183.882 us; speedup 1.0000x reference)
//
#include <hip/hip_runtime.h>

typedef unsigned long long u64;
#define THRESH 0.5f
#define ALL1 0xFFFFFFFFFFFFFFFFull
#define FINF __builtin_inff()

__device__ __forceinline__ u64 shflxU64(u64 v, int m) { return __shfl_xor(v, m, 64); }
// Full bitonic sort of 64 u64 keys (one per lane), ascending across lanes.
__device__ __forceinline__ void sort64(u64 &key, int lane) {
#pragma unroll
    for (int k = 2; k <= 64; k <<= 1) {
#pragma unroll
        for (int j = k >> 1; j > 0; j >>= 1) {
            u64 p = shflxU64(key, j);
            bool takeMax = ((lane & j) != 0) != ((lane & k) != 0);
            u64 mn = key < p ? key : p;
            u64 mx = key < p ? p : key;
            key = takeMax ? mx : mn;
        }
    }
}

// Monotonic (value,id) key: float -> order-preserving u32 (-0 canonicalized to +0
// so float equality == key equality), id in low 32 bits as tiebreak.
__device__ __forceinline__ u64 mkey(float v, int id) {
    v = (v == 0.0f) ? 0.0f : v;
    unsigned u = __float_as_uint(v);
    u ^= (unsigned)((int)u >> 31) | 0x80000000u;
    return ((u64)u << 32) | (unsigned)id;
}

// Block-wide (1024 threads) exclusive prefix sum via wave shfl scan.
// Returns exclusive prefix for this thread; *totalOut = block total.
__device__ __forceinline__ int blockScanExcl1024(int c, int tid, int* wpart,
                                                 int* totalOut) {
    const int lane = tid & 63, wid = tid >> 6;
    int pc = c;
#pragma unroll
    for (int off = 1; off < 64; off <<= 1) {
        int y = __shfl_up(pc, off, 64);
        if (lane >= off) pc += y;
    }
    if (lane == 63) wpart[wid] = pc;
    __syncthreads();
    if (tid < 16) {
        int v = wpart[tid];
#pragma unroll
        for (int off = 1; off < 16; off <<= 1) {
            int y = __shfl_up(v, off, 16);
            if (tid >= off) v += y;
        }
        wpart[tid] = v;   // inclusive over waves
    }
    __syncthreads();
    *totalOut = wpart[15];
    return pc - c + (wid > 0 ? wpart[wid - 1] : 0);
}

// ---------------- K1: zero counters, init, valid scan, appends ----------------
__global__ __launch_bounds__(1024) void k1_scan(
    const float* __restrict__ scores, const float* __restrict__ priorities,
    const int* __restrict__ countPtr, int N, int P,
    float* __restrict__ outPrior, float* __restrict__ outCnt, int* __restrict__ srcWs,
    float* __restrict__ cval, int* __restrict__ csrc, int* __restrict__ meta,
    int* __restrict__ cnt2, int* __restrict__ cnt4)
{
    const int tid = threadIdx.x;
    for (int s = tid; s < P; s += 1024) { outPrior[s] = priorities[s]; srcWs[s] = -1; }
    for (int s = tid; s < N; s += 1024) cnt2[s] = 0;
    for (int s = tid; s < P + N; s += 1024) cnt4[s] = 0;
    int C0 = *countPtr; C0 = C0 < 0 ? 0 : (C0 > P ? P : C0);
    const int per = (N + 1023) >> 10;
    const int i0 = tid * per;
    float sv[16];
    if (per == 16 && i0 + 16 <= N) {
        const float4* s4 = (const float4*)(scores + i0);
        const float4 a = s4[0], b = s4[1], c4 = s4[2], d = s4[3];
        sv[0]=a.x; sv[1]=a.y; sv[2]=a.z; sv[3]=a.w;
        sv[4]=b.x; sv[5]=b.y; sv[6]=b.z; sv[7]=b.w;
        sv[8]=c4.x; sv[9]=c4.y; sv[10]=c4.z; sv[11]=c4.w;
        sv[12]=d.x; sv[13]=d.y; sv[14]=d.z; sv[15]=d.w;
    } else {
#pragma unroll 16
        for (int j = 0; j < 16; ++j)
            sv[j] = (j < per && i0 + j < N) ? scores[i0 + j] : 0.f;
    }
    int c = 0;
#pragma unroll 16
    for (int j = 0; j < 16; ++j) c += (j < per && i0 + j < N && sv[j] > THRESH) ? 1 : 0;
    __shared__ int wpart[16];
    int total;
    int v = blockScanExcl1024(c, tid, wpart, &total);
    int A = P - C0; if (A > total) A = total; if (A < 0) A = 0;
#pragma unroll 16
    for (int j = 0; j < 16; ++j) {
        if (j < per && i0 + j < N) {
            const float sc = sv[j];
            if (sc > THRESH) {
                if (v < A) { outPrior[C0 + v] = sc; srcWs[C0 + v] = i0 + j; }
                else { cval[v - A] = sc; csrc[v - A] = i0 + j; }
                ++v;
            }
        }
    }
    if (tid == 0) {
        meta[0] = total - A;      // M: number of replacement candidates
        meta[1] = C0 + A;         // F: filled pool size after appends
        outCnt[0] = (float)(C0 + A);
    }
}

// ---------------- K2: split dominance count for success condition ----------------
// cnt2[i] = #{V < c_i} + #{j<i : c_j < c_i}; cand i succeeds iff cnt2[i] >= i+1.
#define K2T 512
__global__ __launch_bounds__(256) void k2_count(
    const float* __restrict__ outPrior, const float* __restrict__ cval,
    const int* __restrict__ meta, int* __restrict__ cnt2)
{
    const int M = meta[0], F = meta[1];
    const int iB = blockIdx.x << 8;
    if (iB >= M) return;
    const int hi = min(M, iB + 256);
    const int smax = F + hi;              // exclusive max source index this block needs
    const int tb = blockIdx.y * K2T;
    if (tb >= smax) return;
    const int te = min(smax - tb, K2T);
    __shared__ __align__(16) float tile[K2T];
    for (int t = threadIdx.x; t < K2T; t += 256) {
        const int s = tb + t;
        tile[t] = (t < te) ? ((s < F) ? outPrior[s] : cval[s - F]) : FINF;
    }
    __syncthreads();
    const int i = iB + threadIdx.x;
    if (i >= M) return;
    const float x = cval[i];
    int cnt = 0;
    const float4* t4 = (const float4*)tile;
    if (tb + K2T <= F + iB) {             // full tile for every thread in block
#pragma unroll 8
        for (int q = 0; q < K2T / 4; ++q) {
            const float4 w = t4[q];
            cnt += (w.x < x) + (w.y < x) + (w.z < x) + (w.w < x);
        }
    } else {
        int lim = F + i - tb;
        if (lim < 0) lim = 0;
        if (lim > te) lim = te;
        const int l4 = lim >> 2;
        for (int q = 0; q < l4; ++q) {
            const float4 w = t4[q];
            cnt += (w.x < x) + (w.y < x) + (w.z < x) + (w.w < x);
        }
        for (int t = l4 << 2; t < lim; ++t) cnt += tile[t] < x;
    }
    if (cnt) atomicAdd(&cnt2[i], cnt);
}

// ---------------- K3: succ from cnt2, scan -> write numbers, compact writes ----------------
__global__ __launch_bounds__(1024) void k3_compact(
    const float* __restrict__ cval, const int* __restrict__ csrc,
    const int* __restrict__ cnt2, int* __restrict__ meta,
    float* __restrict__ cvalS, float* __restrict__ wval, int* __restrict__ wsrc,
    int* __restrict__ writeNum)
{
    const int M = meta[0];
    const int tid = threadIdx.x;
    const int per = (M + 1023) >> 10;
    const int i0 = tid * per, i1 = min(i0 + per, M);
    int c = 0;
    for (int i = i0; i < i1; ++i) c += (cnt2[i] >= i + 1) ? 1 : 0;
    __shared__ int wpart[16];
    int total;
    int w = blockScanExcl1024(c, tid, wpart, &total);
    for (int i = i0; i < i1; ++i) {
        if (cnt2[i] >= i + 1) {
            wval[w] = cval[i]; wsrc[w] = csrc[i]; writeNum[i] = w; cvalS[i] = cval[i]; ++w;
        } else { writeNum[i] = -1; cvalS[i] = FINF; }
    }
    if (tid == 0) meta[2] = total;      // R: number of successful writes
}

// ---------------- K4: rank count in W = V ∪ C_succ via u64 monotonic keys ----------------
#define K4T 512
__global__ __launch_bounds__(256) void k4_count(
    const float* __restrict__ outPrior, const float* __restrict__ cvalS,
    const int* __restrict__ meta, int P, int* __restrict__ cnt4)
{
    const int M = meta[0], F = meta[1];
    if (M == 0) return;
    const int tot = F + M;
    const int eB = blockIdx.x << 8;
    if (eB >= tot) return;
    const int tb = blockIdx.y * K4T;
    if (tb >= tot) return;
    const int te = min(tot - tb, K4T);
    __shared__ __align__(16) u64 tile[K4T];
    for (int t = threadIdx.x; t < K4T; t += 256) {
        const int s = tb + t;
        u64 kk = ALL1;
        if (t < te) {
            if (s < F) kk = mkey(outPrior[s], s);
            else       kk = mkey(cvalS[s - F], P + (s - F));
        }
        tile[t] = kk;
    }
    __syncthreads();
    const int e = eB + threadIdx.x;
    if (e >= tot) return;
    float x; int id;
    if (e < F) { x = outPrior[e]; id = e; }
    else {
        x = cvalS[e - F];
        if (x == FINF) return;
        id = P + (e - F);
    }
    const u64 kx = mkey(x, id);
    int cnt = 0;
    const ulonglong2* t2 = (const ulonglong2*)tile;
#pragma unroll 8
    for (int q = 0; q < K4T / 2; ++q) {
        const ulonglong2 w = t2[q];
        cnt += (int)(w.x < kx) + (int)(w.y < kx);
    }
    if (cnt) atomicAdd(&cnt4[e], cnt);
}

// ---------------- K5: scatter + LDS-resident slot-chain resolution + apply ----------------
// Phase 0 (scatter): from final ranks cnt4, emit evicted list (rank < R+64) and
// survivor flags; same-block global write->read ordered by __syncthreads.
// Chain: state[r] payload (27b) = parent rank (unresolved) or slot (resolved);
// MSF = slot known; DONEF = final; TIEF = tie-run member; RSF = run start.
// Tied runs assign members (sorted by current slot ascending) in rank order;
// boundary run straddling R gives its e lowest current slots to the e evictions.
#define SCAP 14400
#define DONEF (1 << 30)
#define MSF   (1 << 29)
#define TIEF  (1 << 28)
#define RSF   (1 << 27)
#define PAYM  ((1 << 27) - 1)
__global__ __launch_bounds__(1024) void k5_chain(
    float* __restrict__ evV, int* __restrict__ evId,
    const int* __restrict__ meta, int P,
    const float* __restrict__ wval, const int* __restrict__ wsrc,
    int* __restrict__ survW,
    float* outPrior, int* __restrict__ srcWs,
    const float* __restrict__ cvalS, const int* __restrict__ writeNum,
    const int* __restrict__ cnt4)
{
    __shared__ int state[SCAP];
    __shared__ int shRp, shLeft;
    const int tid = threadIdx.x;
    const int M = meta[0], F = meta[1], R = meta[2];
    if (M == 0) return;
    const int tot = F + M;

    // ---- Phase 0: scatter evicted list + survivor flags (was k4_scatter) ----
    for (int e = tid; e < tot; e += 1024) {
        float x; int myid; bool isC = false; int wn = -1;
        if (e < F) { x = outPrior[e]; myid = e; }
        else {
            const int i = e - F;
            x = cvalS[i];
            if (x == FINF) continue;
            isC = true; wn = writeNum[i]; myid = P + i;
        }
        const int cnt = cnt4[e];
        if (isC) survW[wn] = (cnt >= R) ? 1 : 0;
        if (cnt < R + 64) { evV[cnt] = x; evId[cnt] = isC ? (P + wn) : myid; }
    }
    __syncthreads();   // orders this block's global writes before reads below

    if (R <= 0 || R > SCAP) return;
    const int Wtot = F + R;

    // Rp: start of the equal-value run straddling the evicted/survivor boundary
    if (tid == 0) {
        int Rp = R;
        if (R < Wtot) {
            const float vR1 = evV[R - 1];
            if (evV[R] == vR1) {
                int rr = R - 1;
                while (rr >= 0 && evV[rr] == vR1) --rr;
                Rp = rr + 1;
            }
        }
        shRp = Rp;
    }
    __syncthreads();
    const int Rp = shRp;

    // init: one coalesced global pass; all later rounds are pure LDS
    for (int r = tid; r < Rp; r += 1024) {
        const float v = evV[r];
        const bool tp = (r > 0) && (evV[r - 1] == v);
        const bool tn = (r + 1 < Rp) && (evV[r + 1] == v);
        const bool tie = tp || tn;
        const int rs = (tie && !tp) ? RSF : 0;
        const int id = evId[r];
        int st;
        if (id < P) st = id | MSF | (tie ? (TIEF | rs) : DONEF);   // root
        else        st = (id - P) | (tie ? (TIEF | rs) : 0);       // parent-encoding
        state[r] = st;
    }
    __syncthreads();

    for (int round = 0; round < Rp + 2; ++round) {
        // walk phase: follow parents in LDS until DONE ancestor or pending tie
        for (int r = tid; r < Rp; r += 1024) {
            const int s = state[r];
            if (s & MSF) continue;
            int p = s & PAYM;
            int ms = -1;
            for (int g = 0; g < Rp + 2; ++g) {
                const int sp = state[p];
                if (sp & DONEF) { ms = sp & PAYM; break; }
                if (sp & (MSF | TIEF)) break;       // blocked: tie pending sort
                const int q = sp & PAYM;
                if (q >= p) break;                  // malformed guard
                p = q;
            }
            if (ms >= 0)
                state[r] = ms | MSF | ((s & TIEF) ? (s & (TIEF | RSF)) : DONEF);
            else
                state[r] = p | (s & (TIEF | RSF));  // path compression
        }
        __syncthreads();
        // run-sort phase: leader = run start; sort member slots ascending
        for (int r = tid; r < Rp; r += 1024) {
            const int s = state[r];
            if (!(s & RSF) || (s & DONEF)) continue;
            int re = r + 1;
            while (re < Rp) {
                const int t = state[re];
                if ((t & TIEF) && !(t & RSF)) ++re; else break;
            }
            bool ready = true;
            for (int q = r; q < re; ++q) ready &= (state[q] & MSF) != 0;
            if (!ready) continue;
            for (int j = r; j < re; ++j) {          // selection sort on payloads
                int best = j;
                for (int q = j + 1; q < re; ++q)
                    if ((state[q] & PAYM) < (state[best] & PAYM)) best = q;
                if (best != j) {
                    const int pj = state[j] & PAYM, pb = state[best] & PAYM;
                    state[j]    = (state[j] & ~PAYM) | pb;
                    state[best] = (state[best] & ~PAYM) | pj;
                }
            }
            for (int j = r; j < re; ++j) state[j] |= DONEF;
        }
        __syncthreads();
        if (tid == 0) shLeft = 0;
        __syncthreads();
        int loc = 0;
        for (int r = tid; r < Rp; r += 1024) loc += (state[r] & DONEF) ? 0 : 1;
        if (loc) atomicAdd(&shLeft, loc);
        __syncthreads();
        if (shLeft == 0) break;
    }
    __syncthreads();

    // boundary run [Rp, R): e evictions take the e smallest current slots
    if (Rp < R && tid < 64) {
        const int lane = tid;
        const int r = Rp + lane;
        const float v0 = evV[Rp];
        const bool mem = (r < Wtot) && (evV[r] == v0);
        const int g = (int)__popcll(__ballot(mem));
        const int e = R - Rp;
        int id = 0, ms = 0;
        if (mem) {
            id = evId[r];
            ms = (id < P) ? id : (state[id - P] & PAYM);
        }
        u64 key = mem ? ((((u64)(unsigned)ms) << 32) | (u64)(unsigned)id) : ALL1;
        sort64(key, lane);
        const int sid = (int)(unsigned)(key & 0xFFFFFFFFull);
        const int sms = (int)(unsigned)(key >> 32);
        const bool real = (key != ALL1) && (lane < g);
        if (real && lane < e) state[Rp + lane] = sms;   // payload-only (flags 0)
        if (real && sid >= P) survW[sid - P] = (lane >= e) ? 1 : 0;
    }
    __syncthreads();

    // apply surviving writes
    for (int j = tid; j < R; j += 1024) {
        if (survW[j]) {
            const int sl = state[j] & PAYM;
            outPrior[sl] = wval[j];
            srcWs[sl] = wsrc[j];
        }
    }
}

// ---------------- gather: one block per pool row ----------------
__global__ __launch_bounds__(256) void gather_kernel(
    const float* __restrict__ summaries,
    const float* __restrict__ pool,
    const int* __restrict__ src,
    float* __restrict__ outPool, int D) {
    int p = blockIdx.x;
    int s = src[p];
    const float* row = (s >= 0) ? (summaries + (size_t)s * D) : (pool + (size_t)p * D);
    float* o = outPool + (size_t)p * D;
    if ((D & 3) == 0) {
        for (int k = (threadIdx.x << 2); k < D; k += (blockDim.x << 2)) {
            float4 v = *(const float4*)(row + k);
            *(float4*)(o + k) = v;
        }
    } else {
        for (int k = threadIdx.x; k < D; k += blockDim.x) o[k] = row[k];
    }
}

extern "C" void kernel_launch(void* const* d_in, const int* in_sizes, int n_in,
                              void* d_out, int out_size, void* d_ws, size_t ws_size,
                              hipStream_t stream) {
    const float* summaries  = (const float*)d_in[0];
    const float* scores     = (const float*)d_in[1];
    const float* pool       = (const float*)d_in[2];
    const float* priorities = (const float*)d_in[3];
    const int*   count      = (const int*)d_in[4];

    int N = in_sizes[1];            // 16384
    int P = in_sizes[3];            // 4096
    int D = in_sizes[0] / N;        // 1024

    float* outPool  = (float*)d_out;
    float* outPrior = outPool + (size_t)P * D;
    float* outCnt   = outPrior + P;
    int*   srcWs    = (int*)d_ws;   // P ints; must survive into gather

    // scratch lives inside outPool: gather fully overwrites it at the end
    float* cval     = outPool;
    int*   csrc     = (int*)outPool + 1 * N;
    float* cvalS    = outPool + 3 * N;
    float* wval     = outPool + 4 * N;
    int*   wsrc     = (int*)outPool + 5 * N;
    int*   writeNum = (int*)outPool + 6 * N;
    float* evV      = outPool + 7 * N;                 // N + 64
    int*   evId     = (int*)outPool + 8 * N + 64;      // N + 64
    int*   survW    = (int*)outPool + 10 * N + 128;    // N
    int*   meta     = (int*)outPool + 11 * N + 128;    // 8
    int*   cnt2     = (int*)outPool + 11 * N + 192;    // N
    int*   cnt4     = (int*)outPool + 12 * N + 192;    // P + N

    const int nb2 = (N + 255) / 256;
    const int nb4 = (P + N + 255) / 256;
    const int ty  = (P + N + K2T - 1) / K2T;           // K2T == K4T == 512

    dim3 g2(nb2, ty), g4(nb4, ty);

    k1_scan<<<1, 1024, 0, stream>>>(scores, priorities, count, N, P,
                                    outPrior, outCnt, srcWs, cval, csrc, meta,
                                    cnt2, cnt4);
    k2_count<<<g2, 256, 0, stream>>>(outPrior, cval, meta, cnt2);
    k3_compact<<<1, 1024, 0, stream>>>(cval, csrc, cnt2, meta, cvalS, wval, wsrc, writeNum);
    k4_count<<<g4, 256, 0, stream>>>(outPrior, cvalS, meta, P, cnt4);
    k5_chain<<<1, 1024, 0, stream>>>(evV, evId, meta, P, wval, wsrc, survW,
                                     outPrior, srcWs, cvalS, writeNum, cnt4);
    gather_kernel<<<P, 256, 0, stream>>>(summaries, pool, srcWs, outPool, D);
}

// Round 9
// 178.367 us; speedup vs baseline: 1.0309x; 1.0309x over previous
//
#include <hip/hip_runtime.h>

typedef unsigned long long u64;
#define THRESH 0.5f
#define ALL1 0xFFFFFFFFFFFFFFFFull
#define FINF __builtin_inff()

#define TOUCHB (1 << 20)
#define CMASK  (TOUCHB - 1)

__device__ __forceinline__ u64 shflxU64(u64 v, int m) { return __shfl_xor(v, m, 64); }
// Full bitonic sort of 64 u64 keys (one per lane), ascending across lanes.
__device__ __forceinline__ void sort64(u64 &key, int lane) {
#pragma unroll
    for (int k = 2; k <= 64; k <<= 1) {
#pragma unroll
        for (int j = k >> 1; j > 0; j >>= 1) {
            u64 p = shflxU64(key, j);
            bool takeMax = ((lane & j) != 0) != ((lane & k) != 0);
            u64 mn = key < p ? key : p;
            u64 mx = key < p ? p : key;
            key = takeMax ? mx : mn;
        }
    }
}

// Monotonic (value,id) key: float -> order-preserving u32 (-0 canonicalized to +0
// so float equality == key equality), id in low 32 bits as tiebreak.
__device__ __forceinline__ u64 mkey(float v, int id) {
    v = (v == 0.0f) ? 0.0f : v;
    unsigned u = __float_as_uint(v);
    u ^= (unsigned)((int)u >> 31) | 0x80000000u;
    return ((u64)u << 32) | (unsigned)id;
}

// Block-wide (1024 threads) exclusive prefix sum via wave shfl scan.
__device__ __forceinline__ int blockScanExcl1024(int c, int tid, int* wpart,
                                                 int* totalOut) {
    const int lane = tid & 63, wid = tid >> 6;
    int pc = c;
#pragma unroll
    for (int off = 1; off < 64; off <<= 1) {
        int y = __shfl_up(pc, off, 64);
        if (lane >= off) pc += y;
    }
    if (lane == 63) wpart[wid] = pc;
    __syncthreads();
    if (tid < 16) {
        int v = wpart[tid];
#pragma unroll
        for (int off = 1; off < 16; off <<= 1) {
            int y = __shfl_up(v, off, 16);
            if (tid >= off) v += y;
        }
        wpart[tid] = v;   // inclusive over waves
    }
    __syncthreads();
    *totalOut = wpart[15];
    return pc - c + (wid > 0 ? wpart[wid - 1] : 0);
}

// ---------------- K1 (17 blocks): b0 = scan+emit; b1..16 = bulk init/zero ----------------
__global__ __launch_bounds__(1024) void k1_scan(
    const float* __restrict__ scores, const float* __restrict__ priorities,
    const int* __restrict__ countPtr, int N, int P,
    float* __restrict__ outPrior, float* __restrict__ outCnt, int* __restrict__ srcWs,
    float* __restrict__ cval, int* __restrict__ csrc, int* __restrict__ meta,
    int* __restrict__ cnt2, int* __restrict__ cnt4, int* __restrict__ tickets)
{
    const int tid = threadIdx.x;
    int C0 = *countPtr; C0 = C0 < 0 ? 0 : (C0 > P ? P : C0);

    if (blockIdx.x != 0) {
        // bulk init across 16 blocks x 1024 threads
        const int bt = (int)(blockIdx.x - 1) * 1024 + tid;
        const int BT = 16 * 1024;
        for (int s = bt; s < C0; s += BT) { outPrior[s] = priorities[s]; srcWs[s] = -1; }
        for (int s = bt; s < N; s += BT) cnt2[s] = 0;
        for (int s = bt; s < P + N; s += BT) cnt4[s] = 0;
        if (bt == 0) tickets[0] = 0;
        return;
    }

    // ---- block 0: valid scan + ordered emit ----
    const int per = (N + 1023) >> 10;
    const int i0 = tid * per;
    float sv[16];
    if (per == 16 && i0 + 16 <= N) {
        const float4* s4 = (const float4*)(scores + i0);
        const float4 a = s4[0], b = s4[1], c4 = s4[2], d = s4[3];
        sv[0]=a.x; sv[1]=a.y; sv[2]=a.z; sv[3]=a.w;
        sv[4]=b.x; sv[5]=b.y; sv[6]=b.z; sv[7]=b.w;
        sv[8]=c4.x; sv[9]=c4.y; sv[10]=c4.z; sv[11]=c4.w;
        sv[12]=d.x; sv[13]=d.y; sv[14]=d.z; sv[15]=d.w;
    } else {
#pragma unroll 16
        for (int j = 0; j < 16; ++j)
            sv[j] = (j < per && i0 + j < N) ? scores[i0 + j] : 0.f;
    }
    int c = 0;
#pragma unroll 16
    for (int j = 0; j < 16; ++j) c += (j < per && i0 + j < N && sv[j] > THRESH) ? 1 : 0;
    __shared__ int wpart[16];
    int total;
    int v = blockScanExcl1024(c, tid, wpart, &total);
    int A = P - C0; if (A > total) A = total; if (A < 0) A = 0;
#pragma unroll 16
    for (int j = 0; j < 16; ++j) {
        if (j < per && i0 + j < N) {
            const float sc = sv[j];
            if (sc > THRESH) {
                if (v < A) { outPrior[C0 + v] = sc; srcWs[C0 + v] = i0 + j; }
                else { cval[v - A] = sc; csrc[v - A] = i0 + j; }
                ++v;
            }
        }
    }
    // default-init the non-appended tail [C0+A, P) (disjoint from init blocks' [0,C0))
    for (int s = C0 + A + tid; s < P; s += 1024) {
        outPrior[s] = priorities[s]; srcWs[s] = -1;
    }
    if (tid == 0) {
        meta[0] = total - A;      // M: number of replacement candidates
        meta[1] = C0 + A;         // F: filled pool size after appends
        outCnt[0] = (float)(C0 + A);
    }
}

// ---------------- K23: dominance count grid + last-block (ticket) compaction ----------------
// cnt2[i] = #{V < c_i} + #{j<i : c_j < c_i}; cand i succeeds iff cnt2[i] >= i+1.
// 1024-thread blocks (1024 elements x 512-source tiles). All blocks take the
// ticket; last block runs the k3 compaction with atomic coherence-reads of cnt2.
#define K2T 512
__global__ __launch_bounds__(1024) void k23(
    const float* __restrict__ outPrior, const float* __restrict__ cval,
    const int* __restrict__ csrc, int* __restrict__ meta,
    int* __restrict__ cnt2, int* __restrict__ tickets,
    float* __restrict__ cvalS, float* __restrict__ wval, int* __restrict__ wsrc,
    int* __restrict__ writeNum)
{
    __shared__ __align__(16) float tile[K2T];
    __shared__ int wpart[16];
    __shared__ int shLast;
    const int tid = threadIdx.x;
    const int M = meta[0], F = meta[1];

    const int iB = (int)blockIdx.x << 10;
    const int tb = (int)blockIdx.y * K2T;
    int te = 0;
    if (iB < M) {
        const int hi = min(M, iB + 1024);
        const int smax = F + hi;          // exclusive max source index this block needs
        if (tb < smax) te = min(smax - tb, K2T);
    }
    if (te > 0) {
        for (int t = tid; t < K2T; t += 1024) {
            const int s = tb + t;
            tile[t] = (t < te) ? ((s < F) ? outPrior[s] : cval[s - F]) : FINF;
        }
        __syncthreads();
        const int i = iB + tid;
        if (i < M) {
            const float x = cval[i];
            int cnt = 0;
            const float4* t4 = (const float4*)tile;
            if (tb + K2T <= F + iB) {     // full tile for every thread in block
#pragma unroll 8
                for (int q = 0; q < K2T / 4; ++q) {
                    const float4 w = t4[q];
                    cnt += (w.x < x) + (w.y < x) + (w.z < x) + (w.w < x);
                }
            } else {
                int lim = F + i - tb;
                if (lim < 0) lim = 0;
                if (lim > te) lim = te;
                const int l4 = lim >> 2;
                for (int q = 0; q < l4; ++q) {
                    const float4 w = t4[q];
                    cnt += (w.x < x) + (w.y < x) + (w.z < x) + (w.w < x);
                }
                for (int t = l4 << 2; t < lim; ++t) cnt += tile[t] < x;
            }
            if (cnt) atomicAdd(&cnt2[i], cnt);
        }
    }
    __syncthreads();   // drains this block's atomics before the ticket
    if (tid == 0)
        shLast = (atomicAdd(&tickets[0], 1) == (int)(gridDim.x * gridDim.y) - 1);
    __syncthreads();
    if (!shLast) return;

    // ---- last block: compaction (identical semantics to k3) ----
    const int per = (M + 1023) >> 10;
    const int i0 = tid * per, i1 = min(i0 + per, M);
    int cv[16];
    int c = 0;
    for (int i = i0, j = 0; i < i1; ++i, ++j) {
        const int q = atomicAdd(&cnt2[i], 0);     // coherence-point read
        cv[j] = q;
        c += (q >= i + 1) ? 1 : 0;
    }
    __syncthreads();
    int total;
    int w = blockScanExcl1024(c, tid, wpart, &total);
    for (int i = i0, j = 0; i < i1; ++i, ++j) {
        if (cv[j] >= i + 1) {
            wval[w] = cval[i]; wsrc[w] = csrc[i]; writeNum[i] = w; cvalS[i] = cval[i]; ++w;
        } else { writeNum[i] = -1; cvalS[i] = FINF; }
    }
    if (tid == 0) meta[2] = total;      // R: number of successful writes
}

// ---------------- K4: rank count via u64 keys + distributed last-touch scatter ----------------
// cnt4[e] packs count (low 20b) + touch counter (high bits). Each live element
// receives exactly TY = ceil(tot/K4T) adds; the last toucher holds the final
// rank and scatters evV/evId/survW immediately (ranks unique -> no conflicts).
#define K4T 512
__global__ __launch_bounds__(256) void k4_count(
    const float* __restrict__ outPrior, const float* __restrict__ cvalS,
    const int* __restrict__ writeNum, const int* __restrict__ meta, int P,
    int* __restrict__ cnt4,
    float* __restrict__ evV, int* __restrict__ evId, int* __restrict__ survW)
{
    const int M = meta[0], F = meta[1];
    if (M == 0) return;
    const int tot = F + M;
    const int eB = (int)blockIdx.x << 8;
    if (eB >= tot) return;
    const int tb = (int)blockIdx.y * K4T;
    if (tb >= tot) return;
    const int te = min(tot - tb, K4T);
    __shared__ __align__(16) u64 tile[K4T];
    for (int t = threadIdx.x; t < K4T; t += 256) {
        const int s = tb + t;
        u64 kk = ALL1;
        if (t < te) {
            if (s < F) kk = mkey(outPrior[s], s);
            else       kk = mkey(cvalS[s - F], P + (s - F));
        }
        tile[t] = kk;
    }
    __syncthreads();
    const int e = eB + threadIdx.x;
    if (e >= tot) return;
    float x; int id; bool isC = false;
    if (e < F) { x = outPrior[e]; id = e; }
    else {
        x = cvalS[e - F];
        if (x == FINF) return;            // dead element: no touches, never scattered
        id = P + (e - F); isC = true;
    }
    const u64 kx = mkey(x, id);
    int cnt = 0;
    const ulonglong2* t2 = (const ulonglong2*)tile;
#pragma unroll 8
    for (int q = 0; q < K4T / 2; ++q) {
        const ulonglong2 w = t2[q];
        cnt += (int)(w.x < kx) + (int)(w.y < kx);
    }
    const int TY = (tot + K4T - 1) / K4T;
    const int old = atomicAdd(&cnt4[e], cnt | TOUCHB);
    if ((old >> 20) == TY - 1) {          // last toucher: final rank in hand
        const int fin = (old & CMASK) + cnt;
        const int R = meta[2];
        if (isC) {
            const int wn = writeNum[e - F];
            survW[wn] = (fin >= R) ? 1 : 0;
            if (fin < R + 64) { evV[fin] = x; evId[fin] = P + wn; }
        } else {
            if (fin < R + 64) { evV[fin] = x; evId[fin] = e; }
        }
    }
}

// ---------------- K5: LDS-resident slot-chain resolution + apply ----------------
// state[r] payload (27b) = parent rank (unresolved) or slot (resolved);
// MSF = slot known; DONEF = final; TIEF = tie-run member; RSF = run start.
// Tied runs assign members (sorted by current slot ascending) in rank order;
// boundary run straddling R gives its e lowest current slots to the e evictions.
#define SCAP 14400
#define DONEF (1 << 30)
#define MSF   (1 << 29)
#define TIEF  (1 << 28)
#define RSF   (1 << 27)
#define PAYM  ((1 << 27) - 1)
__global__ __launch_bounds__(1024) void k5_chain(
    const float* __restrict__ evV, const int* __restrict__ evId,
    const int* __restrict__ meta, int P,
    const float* __restrict__ wval, const int* __restrict__ wsrc,
    int* __restrict__ survW,
    float* outPrior, int* __restrict__ srcWs)
{
    __shared__ int state[SCAP];
    __shared__ int shRp, shLeft;
    const int tid = threadIdx.x;
    const int R = meta[2];
    if (R <= 0 || R > SCAP) return;
    const int F = meta[1];
    const int Wtot = F + R;

    // Rp: start of the equal-value run straddling the evicted/survivor boundary
    if (tid == 0) {
        int Rp = R;
        if (R < Wtot) {
            const float vR1 = evV[R - 1];
            if (evV[R] == vR1) {
                int rr = R - 1;
                while (rr >= 0 && evV[rr] == vR1) --rr;
                Rp = rr + 1;
            }
        }
        shRp = Rp;
    }
    __syncthreads();
    const int Rp = shRp;

    // init: one coalesced global pass; all later rounds are pure LDS
    for (int r = tid; r < Rp; r += 1024) {
        const float v = evV[r];
        const bool tp = (r > 0) && (evV[r - 1] == v);
        const bool tn = (r + 1 < Rp) && (evV[r + 1] == v);
        const bool tie = tp || tn;
        const int rs = (tie && !tp) ? RSF : 0;
        const int id = evId[r];
        int st;
        if (id < P) st = id | MSF | (tie ? (TIEF | rs) : DONEF);   // root
        else        st = (id - P) | (tie ? (TIEF | rs) : 0);       // parent-encoding
        state[r] = st;
    }
    __syncthreads();

    for (int round = 0; round < Rp + 2; ++round) {
        // walk phase: follow parents in LDS until DONE ancestor or pending tie
        for (int r = tid; r < Rp; r += 1024) {
            const int s = state[r];
            if (s & MSF) continue;
            int p = s & PAYM;
            int ms = -1;
            for (int g = 0; g < Rp + 2; ++g) {
                const int sp = state[p];
                if (sp & DONEF) { ms = sp & PAYM; break; }
                if (sp & (MSF | TIEF)) break;       // blocked: tie pending sort
                const int q = sp & PAYM;
                if (q >= p) break;                  // malformed guard
                p = q;
            }
            if (ms >= 0)
                state[r] = ms | MSF | ((s & TIEF) ? (s & (TIEF | RSF)) : DONEF);
            else
                state[r] = p | (s & (TIEF | RSF));  // path compression
        }
        __syncthreads();
        // run-sort phase: leader = run start; sort member slots ascending
        for (int r = tid; r < Rp; r += 1024) {
            const int s = state[r];
            if (!(s & RSF) || (s & DONEF)) continue;
            int re = r + 1;
            while (re < Rp) {
                const int t = state[re];
                if ((t & TIEF) && !(t & RSF)) ++re; else break;
            }
            bool ready = true;
            for (int q = r; q < re; ++q) ready &= (state[q] & MSF) != 0;
            if (!ready) continue;
            for (int j = r; j < re; ++j) {          // selection sort on payloads
                int best = j;
                for (int q = j + 1; q < re; ++q)
                    if ((state[q] & PAYM) < (state[best] & PAYM)) best = q;
                if (best != j) {
                    const int pj = state[j] & PAYM, pb = state[best] & PAYM;
                    state[j]    = (state[j] & ~PAYM) | pb;
                    state[best] = (state[best] & ~PAYM) | pj;
                }
            }
            for (int j = r; j < re; ++j) state[j] |= DONEF;
        }
        __syncthreads();
        if (tid == 0) shLeft = 0;
        __syncthreads();
        int loc = 0;
        for (int r = tid; r < Rp; r += 1024) loc += (state[r] & DONEF) ? 0 : 1;
        if (loc) atomicAdd(&shLeft, loc);
        __syncthreads();
        if (shLeft == 0) break;
    }
    __syncthreads();

    // boundary run [Rp, R): e evictions take the e smallest current slots
    if (Rp < R && tid < 64) {
        const int lane = tid;
        const int r = Rp + lane;
        const float v0 = evV[Rp];
        const bool mem = (r < Wtot) && (evV[r] == v0);
        const int g = (int)__popcll(__ballot(mem));
        const int e = R - Rp;
        int id = 0, ms = 0;
        if (mem) {
            id = evId[r];
            ms = (id < P) ? id : (state[id - P] & PAYM);
        }
        u64 key = mem ? ((((u64)(unsigned)ms) << 32) | (u64)(unsigned)id) : ALL1;
        sort64(key, lane);
        const int sid = (int)(unsigned)(key & 0xFFFFFFFFull);
        const int sms = (int)(unsigned)(key >> 32);
        const bool real = (key != ALL1) && (lane < g);
        if (real && lane < e) state[Rp + lane] = sms;   // payload-only (flags 0)
        if (real && sid >= P) survW[sid - P] = (lane >= e) ? 1 : 0;
    }
    __syncthreads();

    // apply surviving writes
    for (int j = tid; j < R; j += 1024) {
        if (survW[j]) {
            const int sl = state[j] & PAYM;
            outPrior[sl] = wval[j];
            srcWs[sl] = wsrc[j];
        }
    }
}

// ---------------- gather: 1024 blocks x 256 threads, 4 rows per block ----------------
__global__ __launch_bounds__(256) void gather_kernel(
    const float* __restrict__ summaries,
    const float* __restrict__ pool,
    const int* __restrict__ src,
    float* __restrict__ outPool, int P, int D) {
    for (int p = blockIdx.x; p < P; p += gridDim.x) {
        const int s = src[p];
        const float* row = (s >= 0) ? (summaries + (size_t)s * D)
                                    : (pool + (size_t)p * D);
        float* o = outPool + (size_t)p * D;
        if ((D & 3) == 0) {
            const int dq = D >> 2;
            for (int k = threadIdx.x; k < dq; k += blockDim.x)
                ((float4*)o)[k] = ((const float4*)row)[k];
        } else {
            for (int k = threadIdx.x; k < D; k += blockDim.x) o[k] = row[k];
        }
    }
}

extern "C" void kernel_launch(void* const* d_in, const int* in_sizes, int n_in,
                              void* d_out, int out_size, void* d_ws, size_t ws_size,
                              hipStream_t stream) {
    const float* summaries  = (const float*)d_in[0];
    const float* scores     = (const float*)d_in[1];
    const float* pool       = (const float*)d_in[2];
    const float* priorities = (const float*)d_in[3];
    const int*   count      = (const int*)d_in[4];

    int N = in_sizes[1];            // 16384
    int P = in_sizes[3];            // 4096
    int D = in_sizes[0] / N;        // 1024

    float* outPool  = (float*)d_out;
    float* outPrior = outPool + (size_t)P * D;
    float* outCnt   = outPrior + P;
    int*   srcWs    = (int*)d_ws;   // P ints; must survive into gather

    // scratch lives inside outPool: gather fully overwrites it at the end
    float* cval     = outPool;
    int*   csrc     = (int*)outPool + 1 * N;
    float* cvalS    = outPool + 3 * N;
    float* wval     = outPool + 4 * N;
    int*   wsrc     = (int*)outPool + 5 * N;
    int*   writeNum = (int*)outPool + 6 * N;
    float* evV      = outPool + 7 * N;                 // N + 64
    int*   evId     = (int*)outPool + 8 * N + 64;      // N + 64
    int*   survW    = (int*)outPool + 10 * N + 128;    // N
    int*   meta     = (int*)outPool + 11 * N + 128;    // 8
    int*   cnt2     = (int*)outPool + 11 * N + 192;    // N
    int*   cnt4     = (int*)outPool + 12 * N + 192;    // P + N
    int*   tickets  = (int*)outPool + 13 * N + 256;    // 2

    const int ty = (P + N + K2T - 1) / K2T;            // K2T == K4T == 512
    dim3 g23((N + 1023) / 1024, ty);
    dim3 g4((P + N + 255) / 256, ty);

    k1_scan<<<17, 1024, 0, stream>>>(scores, priorities, count, N, P,
                                     outPrior, outCnt, srcWs, cval, csrc, meta,
                                     cnt2, cnt4, tickets);
    k23<<<g23, 1024, 0, stream>>>(outPrior, cval, csrc, meta, cnt2, tickets,
                                  cvalS, wval, wsrc, writeNum);
    k4_count<<<g4, 256, 0, stream>>>(outPrior, cvalS, writeNum, meta, P, cnt4,
                                     evV, evId, survW);
    k5_chain<<<1, 1024, 0, stream>>>(evV, evId, meta, P, wval, wsrc, survW,
                                     outPrior, srcWs);
    gather_kernel<<<1024, 256, 0, stream>>>(summaries, pool, srcWs, outPool, P, D);
}